// Round 8
// baseline (305.183 us; speedup 1.0000x reference)
//
#include <hip/hip_runtime.h>

#define T_LEN 2048
#define B_SZ  2048
#define H_SZ  8
#define WARM  12      // layer l live from tick 3l; outputs from tick 12
#define XS_N  2064

#if defined(__has_builtin)
#  if __has_builtin(__builtin_amdgcn_permlane16_swap) && __has_builtin(__builtin_amdgcn_permlane32_swap)
#    define HAVE_PERMLANE 1
#  endif
#endif
#ifndef HAVE_PERMLANE
#  define HAVE_PERMLANE 0
#endif

#if __has_builtin(__builtin_amdgcn_exp2f)
#  define EXP2F(x) __builtin_amdgcn_exp2f(x)
#else
#  define EXP2F(x) __expf(0.69314718055994531f * (x))
#endif

typedef unsigned int uint2v __attribute__((ext_vector_type(2)));

// row_ror:(CTRL-0x120) within 16-lane rows; 8-periodic data -> rotate mod 8
template<int CTRL>
__device__ __forceinline__ float rot_dpp(float v) {
    return __int_as_float(
        __builtin_amdgcn_update_dpp(0, __float_as_int(v), CTRL, 0xF, 0xF, false));
}

struct TrueT  { static constexpr bool value = true;  };
struct FalseT { static constexpr bool value = false; };

__global__ __launch_bounds__(64, 1)
void rnn_perml(const float* __restrict__ x,
               const float* __restrict__ h0_in,
               const float* __restrict__ w_ih0,
               const float* __restrict__ w_ih,
               const float* __restrict__ w_hh,
               const float* __restrict__ b_ih,
               const float* __restrict__ b_hh,
               const float* __restrict__ w_lin,
               const float* __restrict__ b_lin,
               float* __restrict__ out)
{
    __shared__ __align__(16) float xs[XS_N];

    const int lane = threadIdx.x;
    const int m    = lane & 15;          // offset within row
    const int u    = m & 7;              // hidden unit
    const int row  = lane >> 4;
    const int l    = row ^ (row >> 1);   // layer placement: rows = [L0,L1,L3,L2]
    const int grpB = (m >> 3) & 1;       // A-half: own dot, B-half: export dot
    const int lp   = (l + 3) & 3;        // source layer (row0 <- L3 = output)
    const int srow = lp ^ (lp >> 1);     // its row
    const int bidx = ((srow << 4) | m) << 2;   // bpermute fallback index

    for (int i = lane; i < XS_N; i += 64) xs[i] = 0.0f;
    __syncthreads();
    for (int i = lane; i < T_LEN; i += 64) xs[i] = x[(size_t)i * B_SZ + (B_SZ - 1)];
    __syncthreads();

    // DPP direction probe (HW-verified round 3)
    int rot1 = __builtin_amdgcn_update_dpp(0, lane, 0x121, 0xF, 0xF, false);
    const bool plus = ((rot1 & 15) == ((lane + 1) & 15));

    const float C   = 2.0f * 1.4426950408889634f;  // h=tanh(a) -> r=rcp(exp2(C*a)+1)
    const float m2C = -2.0f * C;

    float whh_rs = 0.0f, wih_rs = 0.0f, wlin_rs = 0.0f;
    #pragma unroll
    for (int j = 0; j < 8; ++j) {
        whh_rs += w_hh[(l * H_SZ + u) * H_SZ + j];
        if (l > 0) wih_rs += w_ih[((l - 1) * H_SZ + u) * H_SZ + j];
        wlin_rs += w_lin[j];
    }
    const float bl_tot = wlin_rs + b_lin[0];

    // A-half lanes: own-recurrence weights; B-half: export weights
    float wd[8];
    #pragma unroll
    for (int s = 0; s < 8; ++s) {
        int j = plus ? ((u + s) & 7) : ((u - s) & 7);
        float wown = m2C * w_hh[(l * H_SZ + u) * H_SZ + j];
        float wexp = (l < 3) ? m2C * w_ih[(l * H_SZ + u) * H_SZ + j] : -2.0f * w_lin[j];
        wd[s] = grpB ? wexp : wown;
    }
    const float tb     = (grpB && l == 3) ? bl_tot : 0.0f;  // output bias on row-3 export
    const float xconst = C * (b_ih[l * H_SZ + u] + b_hh[l * H_SZ + u]
                              + whh_rs + ((l > 0) ? wih_rs : 0.0f));
    const float wx2 = (l == 0) ? C * w_ih0[u] : 0.0f;
    const float sel = (l == 0) ? 0.0f : 1.0f;   // row0's import is the OUTPUT

    // permlane-swap reachability probe: can each lane pull its desired source?
    bool m16x = false, m16y = false, m32x = false, m32y = false, m16any = false;
    bool use_perm = false;
#if HAVE_PERMLANE
    {
        unsigned des = (unsigned)((srow << 4) | m);
        uint2v p16 = __builtin_amdgcn_permlane16_swap((unsigned)lane, (unsigned)lane, false, false);
        uint2v p32 = __builtin_amdgcn_permlane32_swap((unsigned)lane, (unsigned)lane, false, false);
        m16x = (p16.x == des); m16y = (p16.y == des);
        m32x = (p32.x == des); m32y = (p32.y == des);
        m16any = m16x | m16y;
        unsigned long long ok = __ballot((int)(m16any | m32x | m32y));
        use_perm = (ok == ~0ull);
    }
#endif

    // state r = (1 - h)/2
    float r0 = __builtin_fmaf(-0.5f, h0_in[((size_t)l * B_SZ + (B_SZ - 1)) * H_SZ + u], 0.5f);

    auto run = [&](auto PERMC) {
        constexpr bool PERM = decltype(PERMC)::value;
        float r = r0;
        float ipA = 0.0f, ipB = 0.0f;   // import issued at tick k -> consumed k+2

        auto tick = [&](float& ip_slot, float xb, float& outv) -> float {
            // one 8-term serial dot per lane (A: own, B: export E)
            float S = __builtin_fmaf(wd[0], r, tb);
            S = __builtin_fmaf(wd[1], rot_dpp<0x121>(r), S);
            S = __builtin_fmaf(wd[2], rot_dpp<0x122>(r), S);
            S = __builtin_fmaf(wd[3], rot_dpp<0x123>(r), S);
            S = __builtin_fmaf(wd[4], rot_dpp<0x124>(r), S);
            S = __builtin_fmaf(wd[5], rot_dpp<0x125>(r), S);
            S = __builtin_fmaf(wd[6], rot_dpp<0x126>(r), S);
            S = __builtin_fmaf(wd[7], rot_dpp<0x127>(r), S);
            float sw   = rot_dpp<0x128>(S);        // swap halves (xor 8)
            float own  = grpB ? sw : S;            // own-sum everywhere
            float Ef   = grpB ? S  : sw;           // export everywhere
            outv = ip_slot;                        // row0: out[k-12] (bias folded)
            float y  = own + __builtin_fmaf(sel, ip_slot, xb);
            float rn = __builtin_amdgcn_rcpf(EXP2F(y) + 1.0f);
            // exchange: ship Ef to consumer row
            float ipn;
            if constexpr (PERM) {
#if HAVE_PERMLANE
                unsigned Eu = (unsigned)__float_as_int(Ef);
                uint2v e16 = __builtin_amdgcn_permlane16_swap(Eu, Eu, false, false);
                uint2v e32 = __builtin_amdgcn_permlane32_swap(Eu, Eu, false, false);
                float c16 = m16x ? __int_as_float((int)e16.x) : __int_as_float((int)e16.y);
                float c32 = m32x ? __int_as_float((int)e32.x) : __int_as_float((int)e32.y);
                ipn = m16any ? c16 : c32;
#else
                ipn = 0.0f;
#endif
            } else {
                ipn = __int_as_float(__builtin_amdgcn_ds_bpermute(bidx, __float_as_int(Ef)));
            }
            ip_slot = ipn;
            return rn;
        };

        // ---- warm-up ticks 0..11: layer l's r updates only from tick 3l ----
        #pragma unroll
        for (int k = 0; k < WARM; ++k) {
            float dummy;
            float xb = __builtin_fmaf(wx2, xs[k], xconst);
            float rn = (k & 1) ? tick(ipB, xb, dummy) : tick(ipA, xb, dummy);
            r = (k >= 3 * l) ? rn : r;
        }

        // ---- main: ticks 12..2059; tick k emits out[k-12]; x prefetched ----
        const float4* xsv = (const float4*)xs;
        float4 xq = xsv[3];                       // xs[12..15]
        for (int kb = WARM; kb <= 2056; kb += 4) {
            float4 xnxt = xsv[(kb >> 2) + 1];     // prefetch next block
            float ov0, ov1, ov2, ov3;
            r = tick(ipA, __builtin_fmaf(wx2, xq.x, xconst), ov0);
            r = tick(ipB, __builtin_fmaf(wx2, xq.y, xconst), ov1);
            r = tick(ipA, __builtin_fmaf(wx2, xq.z, xconst), ov2);
            r = tick(ipB, __builtin_fmaf(wx2, xq.w, xconst), ov3);
            if (lane == 0)
                *(float4*)(out + (kb - WARM)) = make_float4(ov0, ov1, ov2, ov3);
            xq = xnxt;
        }
    };

    if (use_perm) run(TrueT{});
    else          run(FalseT{});
}

extern "C" void kernel_launch(void* const* d_in, const int* in_sizes, int n_in,
                              void* d_out, int out_size, void* d_ws, size_t ws_size,
                              hipStream_t stream) {
    const float* x     = (const float*)d_in[0];
    const float* h0    = (const float*)d_in[1];
    const float* w_ih0 = (const float*)d_in[2];
    const float* w_ih  = (const float*)d_in[3];
    const float* w_hh  = (const float*)d_in[4];
    const float* b_ih  = (const float*)d_in[5];
    const float* b_hh  = (const float*)d_in[6];
    const float* w_lin = (const float*)d_in[7];
    const float* b_lin = (const float*)d_in[8];
    float* out = (float*)d_out;

    rnn_perml<<<dim3(1), dim3(64), 0, stream>>>(
        x, h0, w_ih0, w_ih, w_hh, b_ih, b_hh, w_lin, b_lin, out);
}

// Round 9
// 230.331 us; speedup vs baseline: 1.3250x; 1.3250x over previous
//
#include <hip/hip_runtime.h>

#define T_LEN 2048
#define B_SZ  2048
#define H_SZ  8
#define WARM  12      // layer l live from tick 3l; outputs from tick 12
#define XS_N  2080    // xs zero-padded; reads up to xs[2067]

#if __has_builtin(__builtin_amdgcn_exp2f)
#  define EXP2F(x) __builtin_amdgcn_exp2f(x)
#else
#  define EXP2F(x) __expf(0.69314718055994531f * (x))
#endif

// row_ror:(CTRL-0x120) within 16-lane rows; 8-periodic data -> rotate mod 8
template<int CTRL>
__device__ __forceinline__ float rot_dpp(float v) {
    return __int_as_float(
        __builtin_amdgcn_update_dpp(0, __float_as_int(v), CTRL, 0xF, 0xF, false));
}

__global__ __launch_bounds__(64, 1)
void rnn_sig2(const float* __restrict__ x,
              const float* __restrict__ h0_in,
              const float* __restrict__ w_ih0,
              const float* __restrict__ w_ih,
              const float* __restrict__ w_hh,
              const float* __restrict__ b_ih,
              const float* __restrict__ b_hh,
              const float* __restrict__ w_lin,
              const float* __restrict__ b_lin,
              float* __restrict__ out)
{
    __shared__ __align__(16) float xs[XS_N];

    const int lane = threadIdx.x;
    const int u    = lane & 7;            // hidden unit
    const int l    = lane >> 4;           // row = layer
    const int grpB = (lane >> 3) & 1;     // A-half: own dot, B-half: export dot
    const int lp   = (l + 3) & 3;         // import source row (row0 <- row3 = output)
    const int bidx = (((lp << 4) | 8 | u)) << 2;   // pull from source row's B-half

    for (int i = lane; i < XS_N; i += 64) xs[i] = 0.0f;
    __syncthreads();
    for (int i = lane; i < T_LEN; i += 64) xs[i] = x[(size_t)i * B_SZ + (B_SZ - 1)];
    __syncthreads();

    // DPP direction probe (HW-verified round 3)
    int rot1 = __builtin_amdgcn_update_dpp(0, lane, 0x121, 0xF, 0xF, false);
    const bool plus = ((rot1 & 15) == ((lane + 1) & 15));

    const float C   = 2.0f * 1.4426950408889634f;  // h=tanh(a) -> r=rcp(exp2(C*a)+1)
    const float m2C = -2.0f * C;

    float whh_rs = 0.0f, wih_rs = 0.0f, wlin_rs = 0.0f;
    #pragma unroll
    for (int j = 0; j < 8; ++j) {
        whh_rs += w_hh[(l * H_SZ + u) * H_SZ + j];
        if (l > 0) wih_rs += w_ih[((l - 1) * H_SZ + u) * H_SZ + j];
        wlin_rs += w_lin[j];
    }
    const float bl_tot = wlin_rs + b_lin[0];

    // per-lane dot weights: A-half = own recurrence (-2C*whh), B-half = export
    float wsel[8];
    #pragma unroll
    for (int s = 0; s < 8; ++s) {
        int j = plus ? ((u + s) & 7) : ((u - s) & 7);
        float whh2  = m2C * w_hh[(l * H_SZ + u) * H_SZ + j];
        float wexp2 = (l < 3) ? m2C * w_ih[(l * H_SZ + u) * H_SZ + j]
                              : -2.0f * w_lin[j];
        wsel[s] = grpB ? wexp2 : whh2;
    }
    const float tbase  = (grpB && l == 3) ? bl_tot : 0.0f;  // output bias on row-3 export
    const float xconst = C * (b_ih[l * H_SZ + u] + b_hh[l * H_SZ + u]
                              + whh_rs + ((l > 0) ? wih_rs : 0.0f));
    const float wx2 = (l == 0) ? C * w_ih0[u] : 0.0f;
    const float sel = (l == 0) ? 0.0f : 1.0f;   // row0's import is the OUTPUT

    // state r = (1 - h)/2
    float r = __builtin_fmaf(-0.5f, h0_in[((size_t)l * B_SZ + (B_SZ - 1)) * H_SZ + u], 0.5f);
    float ipA = 0.0f, ipB = 0.0f;   // import: bperm issued at tick k -> consumed k+2

    // tick: R6-exact critical burst; base precomputed (ip-read + waitcnt OFF the burst)
    auto tick = [&](float& ip_slot, float base) -> float {
        float t0 = __builtin_fmaf(wsel[0], r,  tbase);
        t0 = __builtin_fmaf(wsel[1], rot_dpp<0x121>(r), t0);
        float t1 = wsel[2] * rot_dpp<0x122>(r);
        t1 = __builtin_fmaf(wsel[3], rot_dpp<0x123>(r), t1);
        float t2 = wsel[4] * rot_dpp<0x124>(r);
        t2 = __builtin_fmaf(wsel[5], rot_dpp<0x125>(r), t2);
        float t3 = wsel[6] * rot_dpp<0x126>(r);
        t3 = __builtin_fmaf(wsel[7], rot_dpp<0x127>(r), t3);
        float S  = (t0 + t1) + (t2 + t3);      // A: own-sum, B: export E
        float sw = rot_dpp<0x128>(S);           // swap halves
        float own = grpB ? sw : S;
        float y   = own + base;
        float rn  = __builtin_amdgcn_rcpf(EXP2F(y) + 1.0f);
        ip_slot = __int_as_float(__builtin_amdgcn_ds_bpermute(bidx, __float_as_int(S)));
        return rn;
    };
    auto mkbase = [&](float ip, float xv) -> float {
        return __builtin_fmaf(sel, ip, __builtin_fmaf(wx2, xv, xconst));
    };

    // ---- warm-up ticks 0..11: layer l's r updates only from tick 3l ----
    float baseA = mkbase(0.0f, xs[0]);   // tick 0 (slots start at 0)
    float baseB = 0.0f;
    #pragma unroll
    for (int k = 0; k < WARM; ++k) {
        float rn = (k & 1) ? tick(ipB, baseB) : tick(ipA, baseA);
        r = (k >= 3 * l) ? rn : r;
        if (k & 1) baseA = mkbase(ipA, xs[k + 1]);   // for next (even-slot) tick
        else       baseB = mkbase(ipB, xs[k + 1]);   // for next (odd-slot) tick
    }
    float ov_carry = ipA;   // value consumed at tick 12 -> out[0] (row0)

    // ---- main: ticks 12..2059, 8 per iteration; tick k emits out[k-12] ----
    const float4* xsv = (const float4*)xs;
    float4 xq  = xsv[3];   // xs[12..15]
    float4 xq2 = xsv[4];   // xs[16..19]
    for (int kb = WARM; kb <= 2052; kb += 8) {
        float4 xn1 = xsv[(kb >> 2) + 2];   // xs[kb+8 .. kb+11]
        float4 xn2 = xsv[(kb >> 2) + 3];   // xs[kb+12 .. kb+15]
        float o0 = ov_carry, o1, o2, o3, o4, o5, o6, o7;
        r = tick(ipA, baseA); o1 = ipB; baseB = mkbase(ipB, xq.y);
        r = tick(ipB, baseB); o2 = ipA; baseA = mkbase(ipA, xq.z);
        r = tick(ipA, baseA); o3 = ipB; baseB = mkbase(ipB, xq.w);
        r = tick(ipB, baseB); o4 = ipA; baseA = mkbase(ipA, xq2.x);
        r = tick(ipA, baseA); o5 = ipB; baseB = mkbase(ipB, xq2.y);
        r = tick(ipB, baseB); o6 = ipA; baseA = mkbase(ipA, xq2.z);
        r = tick(ipA, baseA); o7 = ipB; baseB = mkbase(ipB, xq2.w);
        r = tick(ipB, baseB); ov_carry = ipA; baseA = mkbase(ipA, xn1.x);
        if (lane == 0) {
            *(float4*)(out + (kb - WARM))     = make_float4(o0, o1, o2, o3);
            *(float4*)(out + (kb - WARM) + 4) = make_float4(o4, o5, o6, o7);
        }
        xq = xn1; xq2 = xn2;
    }
}

extern "C" void kernel_launch(void* const* d_in, const int* in_sizes, int n_in,
                              void* d_out, int out_size, void* d_ws, size_t ws_size,
                              hipStream_t stream) {
    const float* x     = (const float*)d_in[0];
    const float* h0    = (const float*)d_in[1];
    const float* w_ih0 = (const float*)d_in[2];
    const float* w_ih  = (const float*)d_in[3];
    const float* w_hh  = (const float*)d_in[4];
    const float* b_ih  = (const float*)d_in[5];
    const float* b_hh  = (const float*)d_in[6];
    const float* w_lin = (const float*)d_in[7];
    const float* b_lin = (const float*)d_in[8];
    float* out = (float*)d_out;

    rnn_sig2<<<dim3(1), dim3(64), 0, stream>>>(
        x, h0, w_ih0, w_ih, w_hh, b_ih, b_hh, w_lin, b_lin, out);
}

// Round 10
// 227.546 us; speedup vs baseline: 1.3412x; 1.0122x over previous
//
#include <hip/hip_runtime.h>

#define T_LEN 2048
#define B_SZ  2048
#define H_SZ  8
#define WARM  12      // layer l live from tick 3l; outputs from tick 12
#define XS_N  2080    // xs zero-padded; reads up to xs[2067]

#if __has_builtin(__builtin_amdgcn_exp2f)
#  define EXP2F(x) __builtin_amdgcn_exp2f(x)
#else
#  define EXP2F(x) __expf(0.69314718055994531f * (x))
#endif

// row_ror:(CTRL-0x120) within 16-lane rows; 8-periodic data -> rotate mod 8
template<int CTRL>
__device__ __forceinline__ float rot_dpp(float v) {
    return __int_as_float(
        __builtin_amdgcn_update_dpp(0, __float_as_int(v), CTRL, 0xF, 0xF, false));
}

__global__ __launch_bounds__(64, 1)
void rnn_sig3(const float* __restrict__ x,
              const float* __restrict__ h0_in,
              const float* __restrict__ w_ih0,
              const float* __restrict__ w_ih,
              const float* __restrict__ w_hh,
              const float* __restrict__ b_ih,
              const float* __restrict__ b_hh,
              const float* __restrict__ w_lin,
              const float* __restrict__ b_lin,
              float* __restrict__ out)
{
    __shared__ __align__(16) float xs[XS_N];

    const int lane = threadIdx.x;
    const int u    = lane & 7;            // hidden unit
    const int l    = lane >> 4;           // row = layer
    const bool grB = ((lane >> 3) & 1);   // A-half: own dot (+base), B-half: export dot
    const int lp   = (l + 3) & 3;         // import source row (row0 <- row3 = output)
    const int bidx = (((lp << 4) | 8 | u)) << 2;   // pull from source row's B-half

    for (int i = lane; i < XS_N; i += 64) xs[i] = 0.0f;
    __syncthreads();
    for (int i = lane; i < T_LEN; i += 64) xs[i] = x[(size_t)i * B_SZ + (B_SZ - 1)];
    __syncthreads();

    // DPP direction probe (HW-verified round 3)
    int rot1 = __builtin_amdgcn_update_dpp(0, lane, 0x121, 0xF, 0xF, false);
    const bool plus = ((rot1 & 15) == ((lane + 1) & 15));

    const float C   = 2.0f * 1.4426950408889634f;  // h=tanh(a) -> r=rcp(exp2(C*a)+1)
    const float m2C = -2.0f * C;

    float whh_rs = 0.0f, wih_rs = 0.0f, wlin_rs = 0.0f;
    #pragma unroll
    for (int j = 0; j < 8; ++j) {
        whh_rs += w_hh[(l * H_SZ + u) * H_SZ + j];
        if (l > 0) wih_rs += w_ih[((l - 1) * H_SZ + u) * H_SZ + j];
        wlin_rs += w_lin[j];
    }
    const float bl_tot = wlin_rs + b_lin[0];

    // per-lane dot weights: A-half = own recurrence (-2C*whh), B-half = export
    float wsel[8];
    #pragma unroll
    for (int s = 0; s < 8; ++s) {
        int j = plus ? ((u + s) & 7) : ((u - s) & 7);
        float whh2  = m2C * w_hh[(l * H_SZ + u) * H_SZ + j];
        float wexp2 = (l < 3) ? m2C * w_ih[(l * H_SZ + u) * H_SZ + j]
                              : -2.0f * w_lin[j];
        wsel[s] = grB ? wexp2 : whh2;
    }
    const float tbase  = (grB && l == 3) ? bl_tot : 0.0f;  // output bias on row-3 export
    const float xconst = C * (b_ih[l * H_SZ + u] + b_hh[l * H_SZ + u]
                              + whh_rs + ((l > 0) ? wih_rs : 0.0f));
    const float wx2 = (l == 0) ? C * w_ih0[u] : 0.0f;
    const float sel = (l == 0) ? 0.0f : 1.0f;   // row0's import is the OUTPUT

    // state r = (1 - h)/2
    float r = __builtin_fmaf(-0.5f, h0_in[((size_t)l * B_SZ + (B_SZ - 1)) * H_SZ + u], 0.5f);
    float ipA = 0.0f, ipB = 0.0f;   // import: bperm issued at tick k -> consumed k+2

    // tick: base folded into A-half chain start (B-half keeps tbase -> pure export E).
    // A-half S = y complete; B-half y arrives via ror8(S_A).
    auto tick = [&](float& ip_slot, float base) -> float {
        float start = grB ? tbase : base;                  // off-chain select
        float c0 = __builtin_fmaf(wsel[0], r, start);
        c0 = __builtin_fmaf(wsel[1], rot_dpp<0x121>(r), c0);
        c0 = __builtin_fmaf(wsel[2], rot_dpp<0x122>(r), c0);
        c0 = __builtin_fmaf(wsel[3], rot_dpp<0x123>(r), c0);
        float c1 = wsel[4] * rot_dpp<0x124>(r);
        c1 = __builtin_fmaf(wsel[5], rot_dpp<0x125>(r), c1);
        c1 = __builtin_fmaf(wsel[6], rot_dpp<0x126>(r), c1);
        c1 = __builtin_fmaf(wsel[7], rot_dpp<0x127>(r), c1);
        float S  = c0 + c1;               // A: y (own+base), B: export E
        float sw = rot_dpp<0x128>(S);     // swap halves
        float y  = grB ? sw : S;
        float rn = __builtin_amdgcn_rcpf(EXP2F(y) + 1.0f);
        ip_slot = __int_as_float(__builtin_amdgcn_ds_bpermute(bidx, __float_as_int(S)));
        return rn;
    };
    auto mkbase = [&](float ip, float xv) -> float {
        return __builtin_fmaf(sel, ip, __builtin_fmaf(wx2, xv, xconst));
    };

    // ---- warm-up ticks 0..11: layer l's r updates only from tick 3l ----
    float baseA = mkbase(0.0f, xs[0]);   // tick 0 (slots start at 0)
    float baseB = 0.0f;
    #pragma unroll
    for (int k = 0; k < WARM; ++k) {
        float rn = (k & 1) ? tick(ipB, baseB) : tick(ipA, baseA);
        r = (k >= 3 * l) ? rn : r;
        if (k & 1) baseA = mkbase(ipA, xs[k + 1]);   // for next (even-slot) tick
        else       baseB = mkbase(ipB, xs[k + 1]);   // for next (odd-slot) tick
    }
    float ov_carry = ipA;   // value consumed at tick 12 -> out[0] (row0)

    // ---- main: ticks 12..2059, 8 per iteration; tick k emits out[k-12] ----
    const float4* xsv = (const float4*)xs;
    float4 xq  = xsv[3];   // xs[12..15]
    float4 xq2 = xsv[4];   // xs[16..19]
    for (int kb = WARM; kb <= 2052; kb += 8) {
        float4 xn1 = xsv[(kb >> 2) + 2];   // xs[kb+8 .. kb+11]
        float4 xn2 = xsv[(kb >> 2) + 3];   // xs[kb+12 .. kb+15]
        float o0 = ov_carry, o1, o2, o3, o4, o5, o6, o7;
        r = tick(ipA, baseA); o1 = ipB; baseB = mkbase(ipB, xq.y);
        r = tick(ipB, baseB); o2 = ipA; baseA = mkbase(ipA, xq.z);
        r = tick(ipA, baseA); o3 = ipB; baseB = mkbase(ipB, xq.w);
        r = tick(ipB, baseB); o4 = ipA; baseA = mkbase(ipA, xq2.x);
        r = tick(ipA, baseA); o5 = ipB; baseB = mkbase(ipB, xq2.y);
        r = tick(ipB, baseB); o6 = ipA; baseA = mkbase(ipA, xq2.z);
        r = tick(ipA, baseA); o7 = ipB; baseB = mkbase(ipB, xq2.w);
        r = tick(ipB, baseB); ov_carry = ipA; baseA = mkbase(ipA, xn1.x);
        if (lane == 0) {
            *(float4*)(out + (kb - WARM))     = make_float4(o0, o1, o2, o3);
            *(float4*)(out + (kb - WARM) + 4) = make_float4(o4, o5, o6, o7);
        }
        xq = xn1; xq2 = xn2;
    }
}

extern "C" void kernel_launch(void* const* d_in, const int* in_sizes, int n_in,
                              void* d_out, int out_size, void* d_ws, size_t ws_size,
                              hipStream_t stream) {
    const float* x     = (const float*)d_in[0];
    const float* h0    = (const float*)d_in[1];
    const float* w_ih0 = (const float*)d_in[2];
    const float* w_ih  = (const float*)d_in[3];
    const float* w_hh  = (const float*)d_in[4];
    const float* b_ih  = (const float*)d_in[5];
    const float* b_hh  = (const float*)d_in[6];
    const float* w_lin = (const float*)d_in[7];
    const float* b_lin = (const float*)d_in[8];
    float* out = (float*)d_out;

    rnn_sig3<<<dim3(1), dim3(64), 0, stream>>>(
        x, h0, w_ih0, w_ih, w_hh, b_ih, b_hh, w_lin, b_lin, out);
}

// Round 11
// 214.364 us; speedup vs baseline: 1.4237x; 1.0615x over previous
//
#include <hip/hip_runtime.h>

#define T_LEN 2048
#define B_SZ  2048
#define H_SZ  8
#define WARM  12      // layer l live from tick 3l; outputs from tick 12
#define XS_N  2080    // xs zero-padded; reads up to xs[2067]

#if __has_builtin(__builtin_amdgcn_exp2f)
#  define EXP2F(x) __builtin_amdgcn_exp2f(x)
#else
#  define EXP2F(x) __expf(0.69314718055994531f * (x))
#endif

// row_ror:(CTRL-0x120) within 16-lane rows; 8-periodic data -> rotate mod 8
template<int CTRL>
__device__ __forceinline__ float rot_dpp(float v) {
    return __int_as_float(
        __builtin_amdgcn_update_dpp(0, __float_as_int(v), CTRL, 0xF, 0xF, false));
}

__global__ __launch_bounds__(64, 1)
void rnn_fdpp(const float* __restrict__ x,
              const float* __restrict__ h0_in,
              const float* __restrict__ w_ih0,
              const float* __restrict__ w_ih,
              const float* __restrict__ w_hh,
              const float* __restrict__ b_ih,
              const float* __restrict__ b_hh,
              const float* __restrict__ w_lin,
              const float* __restrict__ b_lin,
              float* __restrict__ out)
{
    __shared__ __align__(16) float xs[XS_N];

    const int lane = threadIdx.x;
    const int u    = lane & 7;            // hidden unit
    const int l    = lane >> 4;           // row = layer
    const bool grB = ((lane >> 3) & 1);   // A-half: own dot (+base), B-half: export dot
    const int lp   = (l + 3) & 3;         // import source row (row0 <- row3 = output)
    const int bidx = (((lp << 4) | 8 | u)) << 2;   // pull from source row's B-half

    for (int i = lane; i < XS_N; i += 64) xs[i] = 0.0f;
    __syncthreads();
    for (int i = lane; i < T_LEN; i += 64) xs[i] = x[(size_t)i * B_SZ + (B_SZ - 1)];
    __syncthreads();

    // DPP direction probe (HW-verified round 3); asm row_ror:s == ctrl 0x120+s
    int rot1 = __builtin_amdgcn_update_dpp(0, lane, 0x121, 0xF, 0xF, false);
    const bool plus = ((rot1 & 15) == ((lane + 1) & 15));

    const float C   = 2.0f * 1.4426950408889634f;  // h=tanh(a) -> r=rcp(exp2(C*a)+1)
    const float m2C = -2.0f * C;

    float whh_rs = 0.0f, wih_rs = 0.0f, wlin_rs = 0.0f;
    #pragma unroll
    for (int j = 0; j < 8; ++j) {
        whh_rs += w_hh[(l * H_SZ + u) * H_SZ + j];
        if (l > 0) wih_rs += w_ih[((l - 1) * H_SZ + u) * H_SZ + j];
        wlin_rs += w_lin[j];
    }
    const float bl_tot = wlin_rs + b_lin[0];

    // per-lane dot weights: A-half = own recurrence (-2C*whh), B-half = export
    float wsel[8];
    #pragma unroll
    for (int s = 0; s < 8; ++s) {
        int j = plus ? ((u + s) & 7) : ((u - s) & 7);
        float whh2  = m2C * w_hh[(l * H_SZ + u) * H_SZ + j];
        float wexp2 = (l < 3) ? m2C * w_ih[(l * H_SZ + u) * H_SZ + j]
                              : -2.0f * w_lin[j];
        wsel[s] = grB ? wexp2 : whh2;
    }
    const float tbase  = (grB && l == 3) ? bl_tot : 0.0f;  // output bias on row-3 export
    const float xconst = C * (b_ih[l * H_SZ + u] + b_hh[l * H_SZ + u]
                              + whh_rs + ((l > 0) ? wih_rs : 0.0f));
    const float wx2 = (l == 0) ? C * w_ih0[u] : 0.0f;
    const float sel = (l == 0) ? 0.0f : 1.0f;   // row0's import is the OUTPUT

    // state r = (1 - h)/2
    float r = __builtin_fmaf(-0.5f, h0_in[((size_t)l * B_SZ + (B_SZ - 1)) * H_SZ + u], 0.5f);
    float ipA = 0.0f, ipB = 0.0f;   // import: bperm issued at tick k -> consumed k+2

    // tick: fused rot+mul via v_fmac_f32_dpp / v_mul_f32_dpp (DPP legal on VOP2).
    // Two interleaved 4-term chains; base folded into A-chain start.
    // s_nop 1 guards the VALU-write -> DPP-read hazards (r from prev rcp; S -> ror8).
    auto tick = [&](float& ip_slot, float base) -> float {
        float c0 = grB ? tbase : base;                  // off-chain select
        float c1, S, sw;
        asm("s_nop 1\n\t"
            "v_fma_f32      %[c0], %[w0], %[r], %[c0]\n\t"
            "v_mul_f32_dpp  %[c1], %[r], %[w4] row_ror:4 row_mask:0xf bank_mask:0xf\n\t"
            "v_fmac_f32_dpp %[c0], %[r], %[w1] row_ror:1 row_mask:0xf bank_mask:0xf\n\t"
            "v_fmac_f32_dpp %[c1], %[r], %[w5] row_ror:5 row_mask:0xf bank_mask:0xf\n\t"
            "v_fmac_f32_dpp %[c0], %[r], %[w2] row_ror:2 row_mask:0xf bank_mask:0xf\n\t"
            "v_fmac_f32_dpp %[c1], %[r], %[w6] row_ror:6 row_mask:0xf bank_mask:0xf\n\t"
            "v_fmac_f32_dpp %[c0], %[r], %[w3] row_ror:3 row_mask:0xf bank_mask:0xf\n\t"
            "v_fmac_f32_dpp %[c1], %[r], %[w7] row_ror:7 row_mask:0xf bank_mask:0xf\n\t"
            "v_add_f32      %[S], %[c0], %[c1]\n\t"
            "s_nop 1\n\t"
            "v_mov_b32_dpp  %[sw], %[S] row_ror:8 row_mask:0xf bank_mask:0xf"
            : [c0]"+v"(c0), [c1]"=&v"(c1), [S]"=&v"(S), [sw]"=&v"(sw)
            : [r]"v"(r), [w0]"v"(wsel[0]), [w1]"v"(wsel[1]), [w2]"v"(wsel[2]),
              [w3]"v"(wsel[3]), [w4]"v"(wsel[4]), [w5]"v"(wsel[5]),
              [w6]"v"(wsel[6]), [w7]"v"(wsel[7]));
        // issue LDS exchange first so its latency overlaps the trans tail
        ip_slot = __int_as_float(__builtin_amdgcn_ds_bpermute(bidx, __float_as_int(S)));
        float y  = grB ? sw : S;         // A: y = own+base, B: y via ror8
        float rn = __builtin_amdgcn_rcpf(EXP2F(y) + 1.0f);
        return rn;
    };
    auto mkbase = [&](float ip, float xv) -> float {
        return __builtin_fmaf(sel, ip, __builtin_fmaf(wx2, xv, xconst));
    };

    // ---- warm-up ticks 0..11: layer l's r updates only from tick 3l ----
    float baseA = mkbase(0.0f, xs[0]);   // tick 0 (slots start at 0)
    float baseB = 0.0f;
    #pragma unroll
    for (int k = 0; k < WARM; ++k) {
        float rn = (k & 1) ? tick(ipB, baseB) : tick(ipA, baseA);
        r = (k >= 3 * l) ? rn : r;
        if (k & 1) baseA = mkbase(ipA, xs[k + 1]);   // for next (even-slot) tick
        else       baseB = mkbase(ipB, xs[k + 1]);   // for next (odd-slot) tick
    }
    float ov_carry = ipA;   // value consumed at tick 12 -> out[0] (row0)

    // ---- main: ticks 12..2059, 8 per iteration; tick k emits out[k-12] ----
    const float4* xsv = (const float4*)xs;
    float4 xq  = xsv[3];   // xs[12..15]
    float4 xq2 = xsv[4];   // xs[16..19]
    for (int kb = WARM; kb <= 2052; kb += 8) {
        float4 xn1 = xsv[(kb >> 2) + 2];   // xs[kb+8 .. kb+11]
        float4 xn2 = xsv[(kb >> 2) + 3];   // xs[kb+12 .. kb+15]
        float o0 = ov_carry, o1, o2, o3, o4, o5, o6, o7;
        r = tick(ipA, baseA); o1 = ipB; baseB = mkbase(ipB, xq.y);
        r = tick(ipB, baseB); o2 = ipA; baseA = mkbase(ipA, xq.z);
        r = tick(ipA, baseA); o3 = ipB; baseB = mkbase(ipB, xq.w);
        r = tick(ipB, baseB); o4 = ipA; baseA = mkbase(ipA, xq2.x);
        r = tick(ipA, baseA); o5 = ipB; baseB = mkbase(ipB, xq2.y);
        r = tick(ipB, baseB); o6 = ipA; baseA = mkbase(ipA, xq2.z);
        r = tick(ipA, baseA); o7 = ipB; baseB = mkbase(ipB, xq2.w);
        r = tick(ipB, baseB); ov_carry = ipA; baseA = mkbase(ipA, xn1.x);
        if (lane == 0) {
            *(float4*)(out + (kb - WARM))     = make_float4(o0, o1, o2, o3);
            *(float4*)(out + (kb - WARM) + 4) = make_float4(o4, o5, o6, o7);
        }
        xq = xn1; xq2 = xn2;
    }
}

extern "C" void kernel_launch(void* const* d_in, const int* in_sizes, int n_in,
                              void* d_out, int out_size, void* d_ws, size_t ws_size,
                              hipStream_t stream) {
    const float* x     = (const float*)d_in[0];
    const float* h0    = (const float*)d_in[1];
    const float* w_ih0 = (const float*)d_in[2];
    const float* w_ih  = (const float*)d_in[3];
    const float* w_hh  = (const float*)d_in[4];
    const float* b_ih  = (const float*)d_in[5];
    const float* b_hh  = (const float*)d_in[6];
    const float* w_lin = (const float*)d_in[7];
    const float* b_lin = (const float*)d_in[8];
    float* out = (float*)d_out;

    rnn_fdpp<<<dim3(1), dim3(64), 0, stream>>>(
        x, h0, w_ih0, w_ih, w_hh, b_ih, b_hh, w_lin, b_lin, out);
}

// Round 13
// 199.631 us; speedup vs baseline: 1.5287x; 1.0738x over previous
//
#include <hip/hip_runtime.h>

#define T_LEN 2048
#define B_SZ  2048
#define H_SZ  8
#define WARM  12      // layer l live from tick 3l; outputs from tick 12
#define XS_N  2080    // xs zero-padded; reads up to xs[2067]

#if __has_builtin(__builtin_amdgcn_exp2f)
#  define EXP2F(x) __builtin_amdgcn_exp2f(x)
#else
#  define EXP2F(x) __expf(0.69314718055994531f * (x))
#endif

// row_ror:(CTRL-0x120) within 16-lane rows; 8-periodic data -> rotate mod 8
template<int CTRL>
__device__ __forceinline__ float rot_dpp(float v) {
    return __int_as_float(
        __builtin_amdgcn_update_dpp(0, __float_as_int(v), CTRL, 0xF, 0xF, false));
}

// ror8 applied ONLY to B-half banks (lanes 8-15 of each 16-row); A-half keeps own.
// Compiler intrinsic -> hazard nops are compiler-managed.
__device__ __forceinline__ float swapB_dpp(float v) {
    return __int_as_float(
        __builtin_amdgcn_update_dpp(__float_as_int(v), __float_as_int(v),
                                    0x128, 0xF, 0xC, false));
}

__global__ __launch_bounds__(64, 1)
void rnn_fdpp3(const float* __restrict__ x,
               const float* __restrict__ h0_in,
               const float* __restrict__ w_ih0,
               const float* __restrict__ w_ih,
               const float* __restrict__ w_hh,
               const float* __restrict__ b_ih,
               const float* __restrict__ b_hh,
               const float* __restrict__ w_lin,
               const float* __restrict__ b_lin,
               float* __restrict__ out)
{
    __shared__ __align__(16) float xs[XS_N];

    const int lane = threadIdx.x;
    const int u    = lane & 7;            // hidden unit
    const int l    = lane >> 4;           // row = layer
    const bool grB = ((lane >> 3) & 1);   // A-half: own dot (+base), B-half: export dot
    const int lp   = (l + 3) & 3;         // import source row (row0 <- row3 = output)
    const int bidx = (((lp << 4) | 8 | u)) << 2;   // pull from source row's B-half

    for (int i = lane; i < XS_N; i += 64) xs[i] = 0.0f;
    __syncthreads();
    for (int i = lane; i < T_LEN; i += 64) xs[i] = x[(size_t)i * B_SZ + (B_SZ - 1)];
    __syncthreads();

    // DPP direction probe (HW-verified round 3); asm row_ror:s == ctrl 0x120+s
    int rot1 = __builtin_amdgcn_update_dpp(0, lane, 0x121, 0xF, 0xF, false);
    const bool plus = ((rot1 & 15) == ((lane + 1) & 15));

    const float C   = 2.0f * 1.4426950408889634f;  // h=tanh(a) -> r=rcp(exp2(C*a)+1)
    const float m2C = -2.0f * C;

    float whh_rs = 0.0f, wih_rs = 0.0f, wlin_rs = 0.0f;
    #pragma unroll
    for (int j = 0; j < 8; ++j) {
        whh_rs += w_hh[(l * H_SZ + u) * H_SZ + j];
        if (l > 0) wih_rs += w_ih[((l - 1) * H_SZ + u) * H_SZ + j];
        wlin_rs += w_lin[j];
    }
    const float bl_tot = wlin_rs + b_lin[0];

    // per-lane dot weights: A-half = own recurrence (-2C*whh), B-half = export
    float wsel[8];
    #pragma unroll
    for (int s = 0; s < 8; ++s) {
        int j = plus ? ((u + s) & 7) : ((u - s) & 7);
        float whh2  = m2C * w_hh[(l * H_SZ + u) * H_SZ + j];
        float wexp2 = (l < 3) ? m2C * w_ih[(l * H_SZ + u) * H_SZ + j]
                              : -2.0f * w_lin[j];
        wsel[s] = grB ? wexp2 : whh2;
    }
    const float tbase = (grB && l == 3) ? bl_tot : 0.0f;   // output bias on row-3 export
    const float xconst_a = C * (b_ih[l * H_SZ + u] + b_hh[l * H_SZ + u]
                                + whh_rs + ((l > 0) ? wih_rs : 0.0f));
    // dual-duty mkbase constants: A-half -> base, B-half -> tbase (no cndmask in loop)
    const float wx2p    = (!grB && l == 0) ? C * w_ih0[u] : 0.0f;
    const float xconstp = grB ? tbase : xconst_a;
    const float selp    = (grB || l == 0) ? 0.0f : 1.0f;   // row0 import = OUTPUT, not y-term

    // state r = (1 - h)/2
    float r = __builtin_fmaf(-0.5f, h0_in[((size_t)l * B_SZ + (B_SZ - 1)) * H_SZ + u], 0.5f);
    float ipA = 0.0f, ipB = 0.0f;   // import: bperm issued at tick k -> consumed k+2

    // tick: s_nop 1 guards VALU(rcp/cndmask)-write -> DPP-read hazard on r (2 wait
    // states required; inline asm is invisible to the compiler's hazard pass —
    // removing it was R12's NaN). 10-op fused-DPP dot; exp2 on S in ALL lanes;
    // bpermute in the exp2 shadow; bank-masked ror8 gives B-half exp2(S_A).
    auto tick = [&](float& ip_slot, float base) -> float {
        float c0 = base;     // A: folded own-base, B: tbase (dual-duty mkbase)
        float c1, S;
        asm("s_nop 1\n\t"
            "v_fma_f32      %[c0], %[w0], %[r], %[c0]\n\t"
            "v_mul_f32_dpp  %[c1], %[r], %[w4] row_ror:4 row_mask:0xf bank_mask:0xf\n\t"
            "v_fmac_f32_dpp %[c0], %[r], %[w1] row_ror:1 row_mask:0xf bank_mask:0xf\n\t"
            "v_fmac_f32_dpp %[c1], %[r], %[w5] row_ror:5 row_mask:0xf bank_mask:0xf\n\t"
            "v_fmac_f32_dpp %[c0], %[r], %[w2] row_ror:2 row_mask:0xf bank_mask:0xf\n\t"
            "v_fmac_f32_dpp %[c1], %[r], %[w6] row_ror:6 row_mask:0xf bank_mask:0xf\n\t"
            "v_fmac_f32_dpp %[c0], %[r], %[w3] row_ror:3 row_mask:0xf bank_mask:0xf\n\t"
            "v_fmac_f32_dpp %[c1], %[r], %[w7] row_ror:7 row_mask:0xf bank_mask:0xf\n\t"
            "v_add_f32      %[S], %[c0], %[c1]"
            : [c0]"+v"(c0), [c1]"=&v"(c1), [S]"=&v"(S)
            : [r]"v"(r), [w0]"v"(wsel[0]), [w1]"v"(wsel[1]), [w2]"v"(wsel[2]),
              [w3]"v"(wsel[3]), [w4]"v"(wsel[4]), [w5]"v"(wsel[5]),
              [w6]"v"(wsel[6]), [w7]"v"(wsel[7]));
        float e = EXP2F(S);              // A: exp2(y); B: exp2(E) (overwritten below)
        ip_slot = __int_as_float(__builtin_amdgcn_ds_bpermute(bidx, __float_as_int(S)));
        float e2 = swapB_dpp(e);         // B-half <- exp2(S_A); A keeps own
        return __builtin_amdgcn_rcpf(e2 + 1.0f);
    };
    auto mkbase = [&](float ip, float xv) -> float {
        return __builtin_fmaf(selp, ip, __builtin_fmaf(wx2p, xv, xconstp));
    };

    // ---- warm-up ticks 0..11: layer l's r updates only from tick 3l ----
    float baseA = mkbase(0.0f, xs[0]);   // tick 0 (slots start at 0)
    float baseB = 0.0f;                  // overwritten after tick 0, before use
    #pragma unroll
    for (int k = 0; k < WARM; ++k) {
        float rn = (k & 1) ? tick(ipB, baseB) : tick(ipA, baseA);
        r = (k >= 3 * l) ? rn : r;
        if (k & 1) baseA = mkbase(ipA, xs[k + 1]);   // for next (even-slot) tick
        else       baseB = mkbase(ipB, xs[k + 1]);   // for next (odd-slot) tick
    }
    float ov_carry = ipA;   // value consumed at tick 12 -> out[0] (row0)

    // ---- main: ticks 12..2059, 8 per iteration; tick k emits out[k-12] ----
    const float4* xsv = (const float4*)xs;
    float4 xq  = xsv[3];   // xs[12..15]
    float4 xq2 = xsv[4];   // xs[16..19]
    for (int kb = WARM; kb <= 2052; kb += 8) {
        float4 xn1 = xsv[(kb >> 2) + 2];   // xs[kb+8 .. kb+11]
        float4 xn2 = xsv[(kb >> 2) + 3];   // xs[kb+12 .. kb+15]
        float o0 = ov_carry, o1, o2, o3, o4, o5, o6, o7;
        r = tick(ipA, baseA); o1 = ipB; baseB = mkbase(ipB, xq.y);
        r = tick(ipB, baseB); o2 = ipA; baseA = mkbase(ipA, xq.z);
        r = tick(ipA, baseA); o3 = ipB; baseB = mkbase(ipB, xq.w);
        r = tick(ipB, baseB); o4 = ipA; baseA = mkbase(ipA, xq2.x);
        r = tick(ipA, baseA); o5 = ipB; baseB = mkbase(ipB, xq2.y);
        r = tick(ipB, baseB); o6 = ipA; baseA = mkbase(ipA, xq2.z);
        r = tick(ipA, baseA); o7 = ipB; baseB = mkbase(ipB, xq2.w);
        r = tick(ipB, baseB); ov_carry = ipA; baseA = mkbase(ipA, xn1.x);
        if (lane == 0) {
            *(float4*)(out + (kb - WARM))     = make_float4(o0, o1, o2, o3);
            *(float4*)(out + (kb - WARM) + 4) = make_float4(o4, o5, o6, o7);
        }
        xq = xn1; xq2 = xn2;
    }
}

extern "C" void kernel_launch(void* const* d_in, const int* in_sizes, int n_in,
                              void* d_out, int out_size, void* d_ws, size_t ws_size,
                              hipStream_t stream) {
    const float* x     = (const float*)d_in[0];
    const float* h0    = (const float*)d_in[1];
    const float* w_ih0 = (const float*)d_in[2];
    const float* w_ih  = (const float*)d_in[3];
    const float* w_hh  = (const float*)d_in[4];
    const float* b_ih  = (const float*)d_in[5];
    const float* b_hh  = (const float*)d_in[6];
    const float* w_lin = (const float*)d_in[7];
    const float* b_lin = (const float*)d_in[8];
    float* out = (float*)d_out;

    rnn_fdpp3<<<dim3(1), dim3(64), 0, stream>>>(
        x, h0, w_ih0, w_ih, w_hh, b_ih, b_hh, w_lin, b_lin, out);
}

// Round 14
// 179.533 us; speedup vs baseline: 1.6999x; 1.1120x over previous
//
#include <hip/hip_runtime.h>

#define T_LEN 2048
#define B_SZ  2048
#define H_SZ  8
#define WARM  12      // layer l live from tick 3l; outputs from tick 12
#define XS_N  2080    // xs zero-padded; reads up to xs[2067]

// row_ror:(CTRL-0x120) within 16-lane rows; 8-periodic data -> rotate mod 8
template<int CTRL>
__device__ __forceinline__ float rot_dpp(float v) {
    return __int_as_float(
        __builtin_amdgcn_update_dpp(0, __float_as_int(v), CTRL, 0xF, 0xF, false));
}

__global__ __launch_bounds__(64, 1)
void rnn_fasm(const float* __restrict__ x,
              const float* __restrict__ h0_in,
              const float* __restrict__ w_ih0,
              const float* __restrict__ w_ih,
              const float* __restrict__ w_hh,
              const float* __restrict__ b_ih,
              const float* __restrict__ b_hh,
              const float* __restrict__ w_lin,
              const float* __restrict__ b_lin,
              float* __restrict__ out)
{
    __shared__ __align__(16) float xs[XS_N];

    const int lane = threadIdx.x;
    const int u    = lane & 7;            // hidden unit
    const int l    = lane >> 4;           // row = layer
    const bool grB = ((lane >> 3) & 1);   // A-half: own dot (+base), B-half: export dot
    const int lp   = (l + 3) & 3;         // import source row (row0 <- row3 = output)
    const int bidx = (((lp << 4) | 8 | u)) << 2;   // pull from source row's B-half

    for (int i = lane; i < XS_N; i += 64) xs[i] = 0.0f;
    __syncthreads();
    for (int i = lane; i < T_LEN; i += 64) xs[i] = x[(size_t)i * B_SZ + (B_SZ - 1)];
    __syncthreads();

    // DPP direction probe (HW-verified round 3); asm row_ror:s == ctrl 0x120+s
    int rot1 = __builtin_amdgcn_update_dpp(0, lane, 0x121, 0xF, 0xF, false);
    const bool plus = ((rot1 & 15) == ((lane + 1) & 15));

    const float C   = 2.0f * 1.4426950408889634f;  // h=tanh(a) -> r=rcp(exp2(C*a)+1)
    const float m2C = -2.0f * C;

    float whh_rs = 0.0f, wih_rs = 0.0f, wlin_rs = 0.0f;
    #pragma unroll
    for (int j = 0; j < 8; ++j) {
        whh_rs += w_hh[(l * H_SZ + u) * H_SZ + j];
        if (l > 0) wih_rs += w_ih[((l - 1) * H_SZ + u) * H_SZ + j];
        wlin_rs += w_lin[j];
    }
    const float bl_tot = wlin_rs + b_lin[0];

    // per-lane dot weights: A-half = own recurrence (-2C*whh), B-half = export
    float wsel[8];
    #pragma unroll
    for (int s = 0; s < 8; ++s) {
        int j = plus ? ((u + s) & 7) : ((u - s) & 7);
        float whh2  = m2C * w_hh[(l * H_SZ + u) * H_SZ + j];
        float wexp2 = (l < 3) ? m2C * w_ih[(l * H_SZ + u) * H_SZ + j]
                              : -2.0f * w_lin[j];
        wsel[s] = grB ? wexp2 : whh2;
    }
    const float tbase = (grB && l == 3) ? bl_tot : 0.0f;   // output bias on row-3 export
    const float xconst_a = C * (b_ih[l * H_SZ + u] + b_hh[l * H_SZ + u]
                                + whh_rs + ((l > 0) ? wih_rs : 0.0f));
    // dual-duty constants: A-half -> base terms, B-half -> tbase (no cndmask in loop)
    const float wx2p    = (!grB && l == 0) ? C * w_ih0[u] : 0.0f;
    const float xconstp = grB ? tbase : xconst_a;
    const float selp    = (grB || l == 0) ? 0.0f : 1.0f;   // row0 import = OUTPUT, not y-term

    // state r = (1 - h)/2
    float r = __builtin_fmaf(-0.5f, h0_in[((size_t)l * B_SZ + (B_SZ - 1)) * H_SZ + u], 0.5f);
    float ipA = 0.0f, ipB = 0.0f;   // import: bperm issued at tick k -> consumed end of k+1

    // Whole tick hand-scheduled in one asm block:
    //  - s_nop 0 + leading non-DPP v_fma = 2 wait states for rcp(r)->DPP(r) hazard
    //  - exp2->DPP(e) hazard slots filled by the independent mkbase half (t) + s_nop 0
    //  - bank-masked ror8 gives B-half exp2(S_A); partial-update keeps A's own exp
    //  - v_add 1.0 via src0 inline constant; rcp closes the sigmoid
    // Outside (off-chain): ds_bpermute issue on S, base = fma(selp, ip_old, t), o-capture.
    auto tick = [&](float& ip_slot, float base, float xv_next, float& t_out) -> float {
        float c0 = base, c1, S, e, t, rn;
        asm("s_nop 0\n\t"
            "v_fma_f32      %[c0], %[w0], %[r], %[c0]\n\t"
            "v_mul_f32_dpp  %[c1], %[r], %[w4] row_ror:4 row_mask:0xf bank_mask:0xf\n\t"
            "v_fmac_f32_dpp %[c0], %[r], %[w1] row_ror:1 row_mask:0xf bank_mask:0xf\n\t"
            "v_fmac_f32_dpp %[c1], %[r], %[w5] row_ror:5 row_mask:0xf bank_mask:0xf\n\t"
            "v_fmac_f32_dpp %[c0], %[r], %[w2] row_ror:2 row_mask:0xf bank_mask:0xf\n\t"
            "v_fmac_f32_dpp %[c1], %[r], %[w6] row_ror:6 row_mask:0xf bank_mask:0xf\n\t"
            "v_fmac_f32_dpp %[c0], %[r], %[w3] row_ror:3 row_mask:0xf bank_mask:0xf\n\t"
            "v_fmac_f32_dpp %[c1], %[r], %[w7] row_ror:7 row_mask:0xf bank_mask:0xf\n\t"
            "v_add_f32      %[S], %[c0], %[c1]\n\t"
            "v_exp_f32      %[e], %[S]\n\t"
            "v_fma_f32      %[t], %[wx], %[xv], %[xc]\n\t"
            "s_nop 0\n\t"
            "v_mov_b32_dpp  %[e], %[e] row_ror:8 row_mask:0xf bank_mask:0xc\n\t"
            "v_add_f32      %[e], 1.0, %[e]\n\t"
            "v_rcp_f32      %[rn], %[e]"
            : [c0]"+v"(c0), [c1]"=&v"(c1), [S]"=&v"(S), [e]"=&v"(e),
              [t]"=&v"(t), [rn]"=&v"(rn)
            : [r]"v"(r), [w0]"v"(wsel[0]), [w1]"v"(wsel[1]), [w2]"v"(wsel[2]),
              [w3]"v"(wsel[3]), [w4]"v"(wsel[4]), [w5]"v"(wsel[5]),
              [w6]"v"(wsel[6]), [w7]"v"(wsel[7]),
              [wx]"v"(wx2p), [xv]"v"(xv_next), [xc]"v"(xconstp));
        ip_slot = __int_as_float(__builtin_amdgcn_ds_bpermute(bidx, __float_as_int(S)));
        t_out = t;
        return rn;
    };

    // ---- warm-up ticks 0..11: layer l's r updates only from tick 3l ----
    float tA, tB;
    float baseA = __builtin_fmaf(wx2p, xs[0], xconstp);  // tick 0 base (ip=0)
    float baseB = 0.0f;                                  // set before first use
    #pragma unroll
    for (int k = 0; k < WARM; ++k) {
        float rn, t;
        if (k & 1) { rn = tick(ipB, baseB, xs[k + 1], t); baseA = __builtin_fmaf(selp, ipA, t); }
        else       { rn = tick(ipA, baseA, xs[k + 1], t); baseB = __builtin_fmaf(selp, ipB, t); }
        r = (k >= 3 * l) ? rn : r;
    }
    float ov_carry = ipA;   // value consumed at tick 12 -> out[0] (row0)
    (void)tA; (void)tB;

    // ---- main: ticks 12..2059, 8 per iteration; tick k emits out[k-12] ----
    const float4* xsv = (const float4*)xs;
    float4 xq  = xsv[3];   // xs[12..15]
    float4 xq2 = xsv[4];   // xs[16..19]
    for (int kb = WARM; kb <= 2052; kb += 8) {
        float4 xn1 = xsv[(kb >> 2) + 2];   // xs[kb+8 .. kb+11]
        float4 xn2 = xsv[(kb >> 2) + 3];   // xs[kb+12 .. kb+15]
        float o0 = ov_carry, o1, o2, o3, o4, o5, o6, o7, t;
        r = tick(ipA, baseA, xq.y,  t); o1 = ipB; baseB = __builtin_fmaf(selp, ipB, t);
        r = tick(ipB, baseB, xq.z,  t); o2 = ipA; baseA = __builtin_fmaf(selp, ipA, t);
        r = tick(ipA, baseA, xq.w,  t); o3 = ipB; baseB = __builtin_fmaf(selp, ipB, t);
        r = tick(ipB, baseB, xq2.x, t); o4 = ipA; baseA = __builtin_fmaf(selp, ipA, t);
        r = tick(ipA, baseA, xq2.y, t); o5 = ipB; baseB = __builtin_fmaf(selp, ipB, t);
        r = tick(ipB, baseB, xq2.z, t); o6 = ipA; baseA = __builtin_fmaf(selp, ipA, t);
        r = tick(ipA, baseA, xq2.w, t); o7 = ipB; baseB = __builtin_fmaf(selp, ipB, t);
        r = tick(ipB, baseB, xn1.x, t); ov_carry = ipA; baseA = __builtin_fmaf(selp, ipA, t);
        if (lane == 0) {
            *(float4*)(out + (kb - WARM))     = make_float4(o0, o1, o2, o3);
            *(float4*)(out + (kb - WARM) + 4) = make_float4(o4, o5, o6, o7);
        }
        xq = xn1; xq2 = xn2;
    }
}

extern "C" void kernel_launch(void* const* d_in, const int* in_sizes, int n_in,
                              void* d_out, int out_size, void* d_ws, size_t ws_size,
                              hipStream_t stream) {
    const float* x     = (const float*)d_in[0];
    const float* h0    = (const float*)d_in[1];
    const float* w_ih0 = (const float*)d_in[2];
    const float* w_ih  = (const float*)d_in[3];
    const float* w_hh  = (const float*)d_in[4];
    const float* b_ih  = (const float*)d_in[5];
    const float* b_hh  = (const float*)d_in[6];
    const float* w_lin = (const float*)d_in[7];
    const float* b_lin = (const float*)d_in[8];
    float* out = (float*)d_out;

    rnn_fasm<<<dim3(1), dim3(64), 0, stream>>>(
        x, h0, w_ih0, w_ih, w_hh, b_ih, b_hh, w_lin, b_lin, out);
}